// Round 4
// baseline (501.356 us; speedup 1.0000x reference)
//
#include <hip/hip_runtime.h>
#include <hip/hip_bf16.h>
#include <hip/hip_cooperative_groups.h>
#include <math.h>

namespace cg = cooperative_groups;

// Problem constants (from reference)
#define B_ROWS 4096
#define C_ROWS 2048
#define D_DIM  2048
#define NUM 2
#define MAX_ITER 15
#define NEAREST 3
#define MARGIN 1.0f

#define GRID_BLOCKS 768   // = 3 blocks/CU * 256 CUs; exactly the GEMM tile count

typedef __bf16 bf16_t;
typedef bf16_t bf16x4 __attribute__((ext_vector_type(4)));
typedef bf16_t bf16x8 __attribute__((ext_vector_type(8)));
typedef float f32x4 __attribute__((ext_vector_type(4)));

// ===========================================================================
// Fused persistent cooperative kernel:
//  phase 0: d_out zero + f32->bf16 conversion + row sumsq (6144 rows / 768 blk)
//  phase 1: both distance GEMMs (768 tiles, 1 per block)
//  phase 2: near3 (3 smallest per Dcc row)
//  phase 3: select (iterative argmin w/ exclusion, first trusted) + atomic mean
// ===========================================================================
__global__ __launch_bounds__(256, 3) void fused_all(
    const float* __restrict__ F, const float* __restrict__ Cn,
    bf16_t* __restrict__ Fb, bf16_t* __restrict__ Cb,
    float* __restrict__ f2, float* __restrict__ c2,
    float* __restrict__ Dfc, float* __restrict__ Dcc,
    int* __restrict__ near3, float* __restrict__ out)
{
    cg::grid_group grid = cg::this_grid();

    __shared__ __align__(16) bf16_t As[128 * 32];
    __shared__ __align__(16) bf16_t Bs[128 * 32];

    const int tid  = threadIdx.x;
    const int wave = tid >> 6;
    const int lane = tid & 63;
    const int bid  = blockIdx.x;

    // ---------------- phase 0: zero out + conv + row sumsq ----------------
    if (bid == 0 && tid == 0) out[0] = 0.0f;
    {
        float* red = (float*)As;   // reuse LDS
        for (int row = bid; row < B_ROWS + C_ROWS; row += GRID_BLOCKS) {
            const float* p;
            bf16_t* q;
            float* sq;
            int r;
            if (row < B_ROWS) {
                r = row; p = F + (size_t)r * D_DIM; q = Fb + (size_t)r * D_DIM; sq = f2;
            } else {
                r = row - B_ROWS; p = Cn + (size_t)r * D_DIM; q = Cb + (size_t)r * D_DIM; sq = c2;
            }
            float s = 0.0f;
            for (int k = tid * 4; k < D_DIM; k += 256 * 4) {
                float4 v = *(const float4*)(p + k);
                s += v.x * v.x + v.y * v.y + v.z * v.z + v.w * v.w;
                bf16x4 b;
                b.x = (bf16_t)v.x; b.y = (bf16_t)v.y; b.z = (bf16_t)v.z; b.w = (bf16_t)v.w;
                *(bf16x4*)(q + k) = b;
            }
            __syncthreads();
            red[tid] = s;
            __syncthreads();
            for (int off = 128; off >= 1; off >>= 1) {
                if (tid < off) red[tid] += red[tid + off];
                __syncthreads();
            }
            if (tid == 0) sq[r] = red[0];
        }
    }
    grid.sync();

    // ---------------- phase 1: distance GEMMs ----------------
    {
        const int by = bid >> 4;           // 0..47
        const int bx = bid & 15;           // 0..15
        const bf16_t* A;
        const float* a2v;
        float* Out;
        int bm;
        if (by < B_ROWS / 128) {
            A = Fb; a2v = f2; Out = Dfc; bm = by * 128;
        } else {
            A = Cb; a2v = c2; Out = Dcc; bm = (by - B_ROWS / 128) * 128;
        }
        const int bn = bx * 128;
        const int N = C_ROWS;
        const int K = D_DIM;

        const int wm = (wave >> 1) * 64;
        const int wn = (wave & 1) * 64;

        f32x4 acc[4][4] = {};

        const int c0   = wave * 2;
        const int rsub = lane >> 2;          // 0..15
        const int ksub = (lane & 3) * 8;     // 0,8,16,24 (16B)
        const int mrow = lane & 15;
        const int kq   = (lane >> 4) * 8;

        for (int k0 = 0; k0 < K; k0 += 32) {
            #pragma unroll
            for (int is = 0; is < 2; ++is) {
                int chunk = c0 + is;
                int row = chunk * 16 + rsub;
                const bf16_t* gA = A + (size_t)(bm + row) * K + (k0 + ksub);
                const bf16_t* gB = Cb + (size_t)(bn + row) * K + (k0 + ksub);
                __builtin_amdgcn_global_load_lds(
                    (const __attribute__((address_space(1))) void*)gA,
                    (__attribute__((address_space(3))) void*)&As[chunk * 512], 16, 0, 0);
                __builtin_amdgcn_global_load_lds(
                    (const __attribute__((address_space(1))) void*)gB,
                    (__attribute__((address_space(3))) void*)&Bs[chunk * 512], 16, 0, 0);
            }
            __syncthreads();

            bf16x8 af[4], bf_[4];
            #pragma unroll
            for (int i = 0; i < 4; ++i) {
                af[i]  = *(const bf16x8*)&As[(wm + i * 16 + mrow) * 32 + kq];
                bf_[i] = *(const bf16x8*)&Bs[(wn + i * 16 + mrow) * 32 + kq];
            }
            #pragma unroll
            for (int i = 0; i < 4; ++i)
                #pragma unroll
                for (int j = 0; j < 4; ++j)
                    acc[i][j] = __builtin_amdgcn_mfma_f32_16x16x32_bf16(af[i], bf_[j], acc[i][j], 0, 0, 0);
            __syncthreads();
        }

        // epilogue: d2 = a2[m] + c2[n] - 2*dot. C/D: col=lane&15, row=(lane>>4)*4+reg
        const int ncol = lane & 15;
        const int r4   = (lane >> 4) * 4;
        #pragma unroll
        for (int i = 0; i < 4; ++i) {
            #pragma unroll
            for (int r = 0; r < 4; ++r) {
                int m = bm + wm + i * 16 + r4 + r;
                float am = a2v[m];
                #pragma unroll
                for (int j = 0; j < 4; ++j) {
                    int n = bn + wn + j * 16 + ncol;
                    Out[(size_t)m * N + n] = am + c2[n] - 2.0f * acc[i][j][r];
                }
            }
        }
    }
    grid.sync();

    // ---------------- phase 2: near3 (one Dcc row per wave) ----------------
    {
        int wid = bid * 4 + wave;          // 0..3071
        if (wid < C_ROWS) {
            const float* row = Dcc + (size_t)wid * C_ROWS;
            float vals[32];
            #pragma unroll
            for (int j = 0; j < 32; ++j) vals[j] = row[lane + j * 64];

            unsigned int excl = 0;
            for (int pick = 0; pick < NEAREST; ++pick) {
                float bestv = INFINITY;
                int bestidx = 0x7fffffff;
                #pragma unroll
                for (int j = 0; j < 32; ++j) {
                    if (excl & (1u << j)) continue;
                    float v = vals[j];
                    int idx = lane + j * 64;
                    if (v < bestv || (v == bestv && idx < bestidx)) { bestv = v; bestidx = idx; }
                }
                for (int off = 32; off >= 1; off >>= 1) {
                    float ov = __shfl_down(bestv, off);
                    int   oi = __shfl_down(bestidx, off);
                    if (ov < bestv || (ov == bestv && oi < bestidx)) { bestv = ov; bestidx = oi; }
                }
                int sel = __shfl(bestidx, 0);
                if (lane == 0) near3[wid * NEAREST + pick] = sel;
                if ((sel & 63) == lane) excl |= 1u << (sel >> 6);
            }
        }
    }
    grid.sync();

    // ---------------- phase 3: select + mean ----------------
    {
        int wid = bid * 4 + wave;          // 0..3071
        for (int b = wid; b < B_ROWS; b += GRID_BLOCKS * 4) {
            int label = b / NUM;
            const float* row = Dfc + (size_t)b * C_ROWS;

            float vals[32];
            #pragma unroll
            for (int j = 0; j < 32; ++j) {
                int cc = lane + j * 64;
                float v = row[cc];
                vals[j] = (cc == label) ? INFINITY : v;
            }

            unsigned int excl = 0;
            float min_diff = 0.0f;
            int found = 0;
            for (int it = 0; it < MAX_ITER; ++it) {
                float bestv = INFINITY;
                int bestidx = 0x7fffffff;
                #pragma unroll
                for (int j = 0; j < 32; ++j) {
                    if (excl & (1u << j)) continue;
                    float v = vals[j];
                    int idx = lane + j * 64;
                    if (v < bestv || (v == bestv && idx < bestidx)) { bestv = v; bestidx = idx; }
                }
                for (int off = 32; off >= 1; off >>= 1) {
                    float ov = __shfl_down(bestv, off);
                    int   oi = __shfl_down(bestidx, off);
                    if (ov < bestv || (ov == bestv && oi < bestidx)) { bestv = ov; bestidx = oi; }
                }
                int sel = __shfl(bestidx, 0);
                float selv = __shfl(bestv, 0);
                bool trusted = (near3[sel * NEAREST + 0] != label) &&
                               (near3[sel * NEAREST + 1] != label) &&
                               (near3[sel * NEAREST + 2] != label);
                if (trusted) {
                    min_diff = sqrtf(fmaxf(selv, 0.0f));
                    found = 1;
                    break;
                }
                if ((sel & 63) == lane) excl |= 1u << (sel >> 6);
            }

            if (lane == 0) {
                float same = sqrtf(fmaxf(row[label], 0.0f));
                float md = found ? min_diff : 0.0f;
                float hinge = fmaxf(MARGIN + same - md, 0.0f);
                atomicAdd(out, hinge * (1.0f / (float)B_ROWS));
            }
        }
    }
}

// ===========================================================================
// Fallback path (non-cooperative), identical math — used only if the
// cooperative launch is rejected.
// ===========================================================================
__global__ __launch_bounds__(256) void conv_rows(const float* __restrict__ F,
                                                 const float* __restrict__ Cn,
                                                 bf16_t* __restrict__ Fb,
                                                 bf16_t* __restrict__ Cb,
                                                 float* __restrict__ f2,
                                                 float* __restrict__ c2,
                                                 float* __restrict__ out) {
    int row = blockIdx.x;
    if (row == 0 && threadIdx.x == 0) out[0] = 0.0f;
    const float* p; bf16_t* q; float* sq; int r;
    if (row < B_ROWS) { r = row; p = F + (size_t)r * D_DIM; q = Fb + (size_t)r * D_DIM; sq = f2; }
    else { r = row - B_ROWS; p = Cn + (size_t)r * D_DIM; q = Cb + (size_t)r * D_DIM; sq = c2; }
    float s = 0.0f;
    for (int k = threadIdx.x * 4; k < D_DIM; k += 256 * 4) {
        float4 v = *(const float4*)(p + k);
        s += v.x * v.x + v.y * v.y + v.z * v.z + v.w * v.w;
        bf16x4 b;
        b.x = (bf16_t)v.x; b.y = (bf16_t)v.y; b.z = (bf16_t)v.z; b.w = (bf16_t)v.w;
        *(bf16x4*)(q + k) = b;
    }
    __shared__ float red[256];
    red[threadIdx.x] = s;
    __syncthreads();
    for (int off = 128; off >= 1; off >>= 1) {
        if ((int)threadIdx.x < off) red[threadIdx.x] += red[threadIdx.x + off];
        __syncthreads();
    }
    if (threadIdx.x == 0) sq[r] = red[0];
}

__global__ __launch_bounds__(256) void gemm_d2_fused(const bf16_t* __restrict__ Fb,
                                                     const bf16_t* __restrict__ Cb,
                                                     const float* __restrict__ f2,
                                                     const float* __restrict__ c2,
                                                     float* __restrict__ Dfc,
                                                     float* __restrict__ Dcc) {
    __shared__ __align__(16) bf16_t As[128 * 32];
    __shared__ __align__(16) bf16_t Bs[128 * 32];
    const int tid  = threadIdx.x;
    const int wave = tid >> 6;
    const int lane = tid & 63;
    const int by = blockIdx.y;
    const bf16_t* A; const float* a2v; float* Out; int bm;
    if (by < B_ROWS / 128) { A = Fb; a2v = f2; Out = Dfc; bm = by * 128; }
    else { A = Cb; a2v = c2; Out = Dcc; bm = (by - B_ROWS / 128) * 128; }
    const int bn = blockIdx.x * 128;
    const int N = C_ROWS, K = D_DIM;
    const int wm = (wave >> 1) * 64, wn = (wave & 1) * 64;
    f32x4 acc[4][4] = {};
    const int c0 = wave * 2, rsub = lane >> 2, ksub = (lane & 3) * 8;
    const int mrow = lane & 15, kq = (lane >> 4) * 8;
    for (int k0 = 0; k0 < K; k0 += 32) {
        #pragma unroll
        for (int is = 0; is < 2; ++is) {
            int chunk = c0 + is;
            int row = chunk * 16 + rsub;
            const bf16_t* gA = A + (size_t)(bm + row) * K + (k0 + ksub);
            const bf16_t* gB = Cb + (size_t)(bn + row) * K + (k0 + ksub);
            __builtin_amdgcn_global_load_lds(
                (const __attribute__((address_space(1))) void*)gA,
                (__attribute__((address_space(3))) void*)&As[chunk * 512], 16, 0, 0);
            __builtin_amdgcn_global_load_lds(
                (const __attribute__((address_space(1))) void*)gB,
                (__attribute__((address_space(3))) void*)&Bs[chunk * 512], 16, 0, 0);
        }
        __syncthreads();
        bf16x8 af[4], bf_[4];
        #pragma unroll
        for (int i = 0; i < 4; ++i) {
            af[i]  = *(const bf16x8*)&As[(wm + i * 16 + mrow) * 32 + kq];
            bf_[i] = *(const bf16x8*)&Bs[(wn + i * 16 + mrow) * 32 + kq];
        }
        #pragma unroll
        for (int i = 0; i < 4; ++i)
            #pragma unroll
            for (int j = 0; j < 4; ++j)
                acc[i][j] = __builtin_amdgcn_mfma_f32_16x16x32_bf16(af[i], bf_[j], acc[i][j], 0, 0, 0);
        __syncthreads();
    }
    const int ncol = lane & 15, r4 = (lane >> 4) * 4;
    #pragma unroll
    for (int i = 0; i < 4; ++i)
        #pragma unroll
        for (int r = 0; r < 4; ++r) {
            int m = bm + wm + i * 16 + r4 + r;
            float am = a2v[m];
            #pragma unroll
            for (int j = 0; j < 4; ++j) {
                int n = bn + wn + j * 16 + ncol;
                Out[(size_t)m * N + n] = am + c2[n] - 2.0f * acc[i][j][r];
            }
        }
}

__global__ __launch_bounds__(256) void near3_kernel(const float* __restrict__ Dcc,
                                                    int* __restrict__ near3, int C) {
    int wave = threadIdx.x >> 6, lane = threadIdx.x & 63;
    int c = blockIdx.x * 4 + wave;
    const float* row = Dcc + (size_t)c * C;
    float vals[32];
    #pragma unroll
    for (int j = 0; j < 32; ++j) vals[j] = row[lane + j * 64];
    unsigned int excl = 0;
    for (int pick = 0; pick < NEAREST; ++pick) {
        float bestv = INFINITY; int bestidx = 0x7fffffff;
        #pragma unroll
        for (int j = 0; j < 32; ++j) {
            if (excl & (1u << j)) continue;
            float v = vals[j]; int idx = lane + j * 64;
            if (v < bestv || (v == bestv && idx < bestidx)) { bestv = v; bestidx = idx; }
        }
        for (int off = 32; off >= 1; off >>= 1) {
            float ov = __shfl_down(bestv, off); int oi = __shfl_down(bestidx, off);
            if (ov < bestv || (ov == bestv && oi < bestidx)) { bestv = ov; bestidx = oi; }
        }
        int sel = __shfl(bestidx, 0);
        if (lane == 0) near3[c * NEAREST + pick] = sel;
        if ((sel & 63) == lane) excl |= 1u << (sel >> 6);
    }
}

__global__ __launch_bounds__(256) void select_kernel(const float* __restrict__ Dfc,
                                                     const int* __restrict__ near3,
                                                     float* __restrict__ out, int C) {
    int wave = threadIdx.x >> 6, lane = threadIdx.x & 63;
    int b = blockIdx.x * 4 + wave;
    int label = b / NUM;
    const float* row = Dfc + (size_t)b * C;
    float vals[32];
    #pragma unroll
    for (int j = 0; j < 32; ++j) {
        int cc = lane + j * 64;
        float v = row[cc];
        vals[j] = (cc == label) ? INFINITY : v;
    }
    unsigned int excl = 0;
    float min_diff = 0.0f;
    int found = 0;
    for (int it = 0; it < MAX_ITER; ++it) {
        float bestv = INFINITY; int bestidx = 0x7fffffff;
        #pragma unroll
        for (int j = 0; j < 32; ++j) {
            if (excl & (1u << j)) continue;
            float v = vals[j]; int idx = lane + j * 64;
            if (v < bestv || (v == bestv && idx < bestidx)) { bestv = v; bestidx = idx; }
        }
        for (int off = 32; off >= 1; off >>= 1) {
            float ov = __shfl_down(bestv, off); int oi = __shfl_down(bestidx, off);
            if (ov < bestv || (ov == bestv && oi < bestidx)) { bestv = ov; bestidx = oi; }
        }
        int sel = __shfl(bestidx, 0);
        float selv = __shfl(bestv, 0);
        bool trusted = (near3[sel * NEAREST + 0] != label) &&
                       (near3[sel * NEAREST + 1] != label) &&
                       (near3[sel * NEAREST + 2] != label);
        if (trusted) { min_diff = sqrtf(fmaxf(selv, 0.0f)); found = 1; break; }
        if ((sel & 63) == lane) excl |= 1u << (sel >> 6);
    }
    __shared__ float hs[4];
    if (lane == 0) {
        float same = sqrtf(fmaxf(row[label], 0.0f));
        float md = found ? min_diff : 0.0f;
        hs[wave] = fmaxf(MARGIN + same - md, 0.0f);
    }
    __syncthreads();
    if (threadIdx.x == 0) {
        float h = hs[0] + hs[1] + hs[2] + hs[3];
        atomicAdd(out, h * (1.0f / (float)B_ROWS));
    }
}

// ---------------------------------------------------------------------------
extern "C" void kernel_launch(void* const* d_in, const int* in_sizes, int n_in,
                              void* d_out, int out_size, void* d_ws, size_t ws_size,
                              hipStream_t stream) {
    const float* feature = (const float*)d_in[0];  // 4096 x 2048
    const float* centers = (const float*)d_in[1];  // 2048 x 2048
    float* out = (float*)d_out;                    // scalar

    // Workspace layout
    float*  Dfc  = (float*)d_ws;                             // 4096*2048 f32
    float*  Dcc  = Dfc + (size_t)B_ROWS * C_ROWS;            // 2048*2048 f32
    bf16_t* Fbf  = (bf16_t*)(Dcc + (size_t)C_ROWS * C_ROWS); // 4096*2048 bf16
    bf16_t* Cbf  = Fbf + (size_t)B_ROWS * D_DIM;             // 2048*2048 bf16
    float*  f2   = (float*)(Cbf + (size_t)C_ROWS * D_DIM);   // 4096
    float*  c2   = f2 + B_ROWS;                              // 2048
    int*    near3 = (int*)(c2 + C_ROWS);                     // 2048*3

    void* args[] = { (void*)&feature, (void*)&centers, (void*)&Fbf, (void*)&Cbf,
                     (void*)&f2, (void*)&c2, (void*)&Dfc, (void*)&Dcc,
                     (void*)&near3, (void*)&out };
    hipError_t err = hipLaunchCooperativeKernel((const void*)fused_all,
                                                dim3(GRID_BLOCKS), dim3(256),
                                                args, 0, stream);
    if (err != hipSuccess) {
        // Fallback: non-cooperative 4-dispatch path (same math).
        conv_rows<<<B_ROWS + C_ROWS, 256, 0, stream>>>(feature, centers, Fbf, Cbf, f2, c2, out);
        gemm_d2_fused<<<dim3(C_ROWS / 128, B_ROWS / 128 + C_ROWS / 128), 256, 0, stream>>>(
            Fbf, Cbf, f2, c2, Dfc, Dcc);
        near3_kernel<<<C_ROWS / 4, 256, 0, stream>>>(Dcc, near3, C_ROWS);
        select_kernel<<<B_ROWS / 4, 256, 0, stream>>>(Dfc, near3, out, C_ROWS);
    }
}

// Round 5
// 200.819 us; speedup vs baseline: 2.4966x; 2.4966x over previous
//
#include <hip/hip_runtime.h>
#include <hip/hip_bf16.h>
#include <math.h>

// Problem constants (from reference)
#define B_ROWS 4096
#define C_ROWS 2048
#define D_DIM  2048
#define NUM 2
#define MAX_ITER 15
#define NEAREST 3
#define MARGIN 1.0f

typedef __bf16 bf16_t;
typedef bf16_t bf16x8 __attribute__((ext_vector_type(8)));
typedef float f32x4 __attribute__((ext_vector_type(4)));

// ---------------------------------------------------------------------------
// conv: one wave per row, f32 -> bf16 (16B stores) + row sumsq via shuffle.
// Rows [0,4096) = feature, [4096,6144) = centers. 4 waves/block.
// ---------------------------------------------------------------------------
__global__ __launch_bounds__(256) void conv_rows(const float* __restrict__ F,
                                                 const float* __restrict__ Cn,
                                                 bf16_t* __restrict__ Fb,
                                                 bf16_t* __restrict__ Cb,
                                                 float* __restrict__ f2,
                                                 float* __restrict__ c2) {
    int wave = threadIdx.x >> 6;
    int lane = threadIdx.x & 63;
    int row = blockIdx.x * 4 + wave;          // 0..6143
    const float* p; bf16_t* q; float* sq; int r;
    if (row < B_ROWS) {
        r = row; p = F + (size_t)r * D_DIM; q = Fb + (size_t)r * D_DIM; sq = f2;
    } else {
        r = row - B_ROWS; p = Cn + (size_t)r * D_DIM; q = Cb + (size_t)r * D_DIM; sq = c2;
    }
    float s = 0.0f;
    #pragma unroll
    for (int it = 0; it < 4; ++it) {
        int k = (it * 64 + lane) * 8;         // 8 consecutive floats per lane
        float4 v0 = *(const float4*)(p + k);
        float4 v1 = *(const float4*)(p + k + 4);
        s += v0.x * v0.x + v0.y * v0.y + v0.z * v0.z + v0.w * v0.w;
        s += v1.x * v1.x + v1.y * v1.y + v1.z * v1.z + v1.w * v1.w;
        bf16x8 b;
        b[0] = (bf16_t)v0.x; b[1] = (bf16_t)v0.y; b[2] = (bf16_t)v0.z; b[3] = (bf16_t)v0.w;
        b[4] = (bf16_t)v1.x; b[5] = (bf16_t)v1.y; b[6] = (bf16_t)v1.z; b[7] = (bf16_t)v1.w;
        *(bf16x8*)(q + k) = b;
    }
    #pragma unroll
    for (int off = 32; off >= 1; off >>= 1) s += __shfl_down(s, off);
    if (lane == 0) sq[r] = s;
}

// ---------------------------------------------------------------------------
// Fused bf16 MFMA distance GEMM (Dfc and Dcc in one dispatch), BK=64:
//   Out[m][n] = a2[m] + c2[n] - 2 * sum_k A[m][k]*Cb[n][k]
// 128x128 tile, 4 waves (2x2 of 64x64), 16x16x32 MFMA. LDS 2x16KB.
// Half the barrier drains of the BK=32 version.
// ---------------------------------------------------------------------------
__global__ __launch_bounds__(256) void gemm_d2_fused(const bf16_t* __restrict__ Fb,
                                                     const bf16_t* __restrict__ Cb,
                                                     const float* __restrict__ f2,
                                                     const float* __restrict__ c2,
                                                     float* __restrict__ Dfc,
                                                     float* __restrict__ Dcc) {
    __shared__ __align__(16) bf16_t As[128 * 64];
    __shared__ __align__(16) bf16_t Bs[128 * 64];

    const int tid  = threadIdx.x;
    const int wave = tid >> 6;
    const int lane = tid & 63;

    const int by = blockIdx.y;
    const bf16_t* A; const float* a2v; float* Out; int bm;
    if (by < B_ROWS / 128) { A = Fb; a2v = f2; Out = Dfc; bm = by * 128; }
    else { A = Cb; a2v = c2; Out = Dcc; bm = (by - B_ROWS / 128) * 128; }
    const int bn = blockIdx.x * 128;
    const int N = C_ROWS, K = D_DIM;

    const int wm = (wave >> 1) * 64;
    const int wn = (wave & 1) * 64;

    f32x4 acc[4][4] = {};

    // Staging (BK=64): one global_load_lds covers 8 rows (64 lanes x 16B =
    // 1024B = 8 x 128B rows). 16 chunks per matrix; wave w stages 4w..4w+3.
    // Lane l: row chunk*8 + (l>>3), k-elems (l&7)*8. LDS dest = chunk*512
    // elems + implicit lane*16B (contiguous row-major — matches layout).
    const int c0   = wave * 4;
    const int rsub = lane >> 3;           // 0..7
    const int ksub = (lane & 7) * 8;      // 0..56
    const int mrow = lane & 15;
    const int kq   = (lane >> 4) * 8;

    for (int k0 = 0; k0 < K; k0 += 64) {
        #pragma unroll
        for (int is = 0; is < 4; ++is) {
            int chunk = c0 + is;
            int row = chunk * 8 + rsub;
            const bf16_t* gA = A + (size_t)(bm + row) * K + (k0 + ksub);
            const bf16_t* gB = Cb + (size_t)(bn + row) * K + (k0 + ksub);
            __builtin_amdgcn_global_load_lds(
                (const __attribute__((address_space(1))) void*)gA,
                (__attribute__((address_space(3))) void*)&As[chunk * 512], 16, 0, 0);
            __builtin_amdgcn_global_load_lds(
                (const __attribute__((address_space(1))) void*)gB,
                (__attribute__((address_space(3))) void*)&Bs[chunk * 512], 16, 0, 0);
        }
        __syncthreads();

        #pragma unroll
        for (int h = 0; h < 2; ++h) {
            bf16x8 af[4], bf_[4];
            #pragma unroll
            for (int i = 0; i < 4; ++i) {
                af[i]  = *(const bf16x8*)&As[(wm + i * 16 + mrow) * 64 + h * 32 + kq];
                bf_[i] = *(const bf16x8*)&Bs[(wn + i * 16 + mrow) * 64 + h * 32 + kq];
            }
            #pragma unroll
            for (int i = 0; i < 4; ++i)
                #pragma unroll
                for (int j = 0; j < 4; ++j)
                    acc[i][j] = __builtin_amdgcn_mfma_f32_16x16x32_bf16(af[i], bf_[j], acc[i][j], 0, 0, 0);
        }
        __syncthreads();
    }

    // Epilogue: d2 = a2[m] + c2[n] - 2*dot. C/D: col=lane&15, row=(lane>>4)*4+reg
    const int ncol = lane & 15;
    const int r4   = (lane >> 4) * 4;
    #pragma unroll
    for (int i = 0; i < 4; ++i) {
        #pragma unroll
        for (int r = 0; r < 4; ++r) {
            int m = bm + wm + i * 16 + r4 + r;
            float am = a2v[m];
            #pragma unroll
            for (int j = 0; j < 4; ++j) {
                int n = bn + wn + j * 16 + ncol;
                Out[(size_t)m * N + n] = am + c2[n] - 2.0f * acc[i][j][r];
            }
        }
    }
}

// ---------------------------------------------------------------------------
// near3: indices of 3 smallest per Dcc row. 4 waves/block, one row per wave.
// ---------------------------------------------------------------------------
__global__ __launch_bounds__(256) void near3_kernel(const float* __restrict__ Dcc,
                                                    int* __restrict__ near3, int C) {
    int wave = threadIdx.x >> 6, lane = threadIdx.x & 63;
    int c = blockIdx.x * 4 + wave;
    const float* row = Dcc + (size_t)c * C;
    float vals[32];
    #pragma unroll
    for (int j = 0; j < 32; ++j) vals[j] = row[lane + j * 64];
    unsigned int excl = 0;
    for (int pick = 0; pick < NEAREST; ++pick) {
        float bestv = INFINITY; int bestidx = 0x7fffffff;
        #pragma unroll
        for (int j = 0; j < 32; ++j) {
            if (excl & (1u << j)) continue;
            float v = vals[j]; int idx = lane + j * 64;
            if (v < bestv || (v == bestv && idx < bestidx)) { bestv = v; bestidx = idx; }
        }
        for (int off = 32; off >= 1; off >>= 1) {
            float ov = __shfl_down(bestv, off); int oi = __shfl_down(bestidx, off);
            if (ov < bestv || (ov == bestv && oi < bestidx)) { bestv = ov; bestidx = oi; }
        }
        int sel = __shfl(bestidx, 0);
        if (lane == 0) near3[c * NEAREST + pick] = sel;
        if ((sel & 63) == lane) excl |= 1u << (sel >> 6);
    }
}

// ---------------------------------------------------------------------------
// select: per feature row, iterative argmin w/ exclusion, first trusted.
// 4 waves/block; block writes ONE partial (no global atomic contention).
// ---------------------------------------------------------------------------
__global__ __launch_bounds__(256) void select_kernel(const float* __restrict__ Dfc,
                                                     const int* __restrict__ near3,
                                                     float* __restrict__ hpart, int C) {
    int wave = threadIdx.x >> 6, lane = threadIdx.x & 63;
    int b = blockIdx.x * 4 + wave;
    int label = b / NUM;
    const float* row = Dfc + (size_t)b * C;
    float vals[32];
    #pragma unroll
    for (int j = 0; j < 32; ++j) {
        int cc = lane + j * 64;
        float v = row[cc];
        vals[j] = (cc == label) ? INFINITY : v;
    }
    unsigned int excl = 0;
    float min_diff = 0.0f;
    int found = 0;
    for (int it = 0; it < MAX_ITER; ++it) {
        float bestv = INFINITY; int bestidx = 0x7fffffff;
        #pragma unroll
        for (int j = 0; j < 32; ++j) {
            if (excl & (1u << j)) continue;
            float v = vals[j]; int idx = lane + j * 64;
            if (v < bestv || (v == bestv && idx < bestidx)) { bestv = v; bestidx = idx; }
        }
        for (int off = 32; off >= 1; off >>= 1) {
            float ov = __shfl_down(bestv, off); int oi = __shfl_down(bestidx, off);
            if (ov < bestv || (ov == bestv && oi < bestidx)) { bestv = ov; bestidx = oi; }
        }
        int sel = __shfl(bestidx, 0);
        float selv = __shfl(bestv, 0);
        bool trusted = (near3[sel * NEAREST + 0] != label) &&
                       (near3[sel * NEAREST + 1] != label) &&
                       (near3[sel * NEAREST + 2] != label);
        if (trusted) { min_diff = sqrtf(fmaxf(selv, 0.0f)); found = 1; break; }
        if ((sel & 63) == lane) excl |= 1u << (sel >> 6);
    }
    __shared__ float hs[4];
    if (lane == 0) {
        float same = sqrtf(fmaxf(row[label], 0.0f));
        float md = found ? min_diff : 0.0f;
        hs[wave] = fmaxf(MARGIN + same - md, 0.0f);
    }
    __syncthreads();
    if (threadIdx.x == 0) hpart[blockIdx.x] = hs[0] + hs[1] + hs[2] + hs[3];
}

// ---------------------------------------------------------------------------
// finalize: sum 1024 partials, write mean. One block.
// ---------------------------------------------------------------------------
__global__ __launch_bounds__(256) void finalize_kernel(const float* __restrict__ hpart,
                                                       float* __restrict__ out, int n) {
    int wave = threadIdx.x >> 6, lane = threadIdx.x & 63;
    float s = 0.0f;
    for (int i = threadIdx.x; i < n; i += 256) s += hpart[i];
    #pragma unroll
    for (int off = 32; off >= 1; off >>= 1) s += __shfl_down(s, off);
    __shared__ float red[4];
    if (lane == 0) red[wave] = s;
    __syncthreads();
    if (threadIdx.x == 0)
        out[0] = (red[0] + red[1] + red[2] + red[3]) * (1.0f / (float)B_ROWS);
}

// ---------------------------------------------------------------------------
extern "C" void kernel_launch(void* const* d_in, const int* in_sizes, int n_in,
                              void* d_out, int out_size, void* d_ws, size_t ws_size,
                              hipStream_t stream) {
    const float* feature = (const float*)d_in[0];  // 4096 x 2048
    const float* centers = (const float*)d_in[1];  // 2048 x 2048
    float* out = (float*)d_out;                    // scalar

    // Workspace layout
    float*  Dfc  = (float*)d_ws;                             // 4096*2048 f32
    float*  Dcc  = Dfc + (size_t)B_ROWS * C_ROWS;            // 2048*2048 f32
    bf16_t* Fbf  = (bf16_t*)(Dcc + (size_t)C_ROWS * C_ROWS); // 4096*2048 bf16
    bf16_t* Cbf  = Fbf + (size_t)B_ROWS * D_DIM;             // 2048*2048 bf16
    float*  f2   = (float*)(Cbf + (size_t)C_ROWS * D_DIM);   // 4096
    float*  c2   = f2 + B_ROWS;                              // 2048
    int*    near3 = (int*)(c2 + C_ROWS);                     // 2048*3
    float*  hpart = (float*)(near3 + C_ROWS * NEAREST);      // 1024

    conv_rows<<<(B_ROWS + C_ROWS) / 4, 256, 0, stream>>>(feature, centers, Fbf, Cbf, f2, c2);

    // Both distance matrices in one dispatch: grid (16, 32+16) = 768 blocks.
    gemm_d2_fused<<<dim3(C_ROWS / 128, B_ROWS / 128 + C_ROWS / 128), 256, 0, stream>>>(
        Fbf, Cbf, f2, c2, Dfc, Dcc);

    near3_kernel<<<C_ROWS / 4, 256, 0, stream>>>(Dcc, near3, C_ROWS);

    select_kernel<<<B_ROWS / 4, 256, 0, stream>>>(Dfc, near3, hpart, C_ROWS);

    finalize_kernel<<<1, 256, 0, stream>>>(hpart, out, B_ROWS / 4);
}